// Round 10
// baseline (35.793 us; speedup 1.0000x reference)
//
#include <hip/hip_runtime.h>

// FutureEncoder: out[b,t,:] = sum_j softmax_j(dot(x[b,t], x[b,t+1+j])) * x[b,t+1+j],
// j in [0,16), valid iff t+1+j < S. fp32 throughout.
//
// Round 10: R8's low-traffic LDS sharing + a REAL async pipeline. R8's
// __syncthreads drained vmcnt(0), waiting on the just-issued next-chunk
// prefetch -> every chunk exposed full L3 latency. Here: 4-slot LDS ring,
// chunks of 4 rows, counted s_waitcnt vmcnt(4/2/0) + raw s_barrier so two
// chunks stay in flight ACROSS each barrier (T3/T4 pattern). Ring safety:
// stage(c+3) writes slot (c+3)%4, last read at iter c-1, and all waves
// passed the iter-c barrier after that read.

namespace {
constexpr int kB     = 2;
constexpr int kS     = 4096;
constexpr int kH     = 1024;
constexpr int kK     = 16;
constexpr int kWaves = 8;                 // 512 threads
constexpr int kTPW   = 2;                 // t's per wave
constexpr int kTPB   = kWaves * kTPW;     // 16 t's per block
constexpr int kRows  = kTPB + kK;         // 32 union rows
constexpr int kCH    = 4;                 // rows per chunk
constexpr int kChunks = kRows / kCH;      // 8
constexpr int kSlots = 4;                 // LDS ring slots (64 KB total)
constexpr int kFR    = kH / (64 * 4);     // 4 float4 fragments per lane per row
constexpr int kBlocks = kB * kS / kTPB;   // 512 -> 2 blocks/CU
constexpr int kXCD   = 8;
}

__global__ __launch_bounds__(512, 4)
void future_encoder_kernel(const float* __restrict__ x, float* __restrict__ out) {
  __shared__ float lds[kSlots][kCH][kH];           // 64 KB ring
  const int lane = (int)(threadIdx.x & 63);
  const int wid  = (int)(threadIdx.x >> 6);        // 0..7

  // XCD strip swizzle (512 % 8 == 0 -> bijective)
  const int vb  = (int)(blockIdx.x % kXCD) * (kBlocks / kXCD) + (int)(blockIdx.x / kXCD);
  const int t0g = vb * kTPB;
  const int b   = t0g / kS;
  const int t0  = t0g % kS;                        // 16 | 4096: no batch crossing
  const float* __restrict__ xb = x   + (size_t)b * kS * kH;
  float* __restrict__       ob = out + (size_t)b * kS * kH;
  const int col = lane * 4;
  const int tw  = kTPW * wid;                      // wave's first t (block-relative)

  // Per-wave state
  float4 xt[kTPW][kFR];
  float  m[kTPW], s[kTPW];
  float4 acc[kTPW][kFR];
#pragma unroll
  for (int tt = 0; tt < kTPW; ++tt) {
    m[tt] = -1e30f;
    s[tt] = 0.f;
#pragma unroll
    for (int p = 0; p < kFR; ++p) {
      acc[tt][p] = make_float4(0.f, 0.f, 0.f, 0.f);
      xt[tt][p]  = make_float4(0.f, 0.f, 0.f, 0.f);
    }
  }

  // Stage chunk c: 16 x 1KB pieces (4 rows x 4 segs); wave stages ids {2w, 2w+1}.
  auto stage = [&](int c) {
#pragma unroll
    for (int k = 0; k < 2; ++k) {
      const int id  = 2 * wid + k;
      const int row = id >> 2;                     // 0..3 within chunk
      const int seg = id & 3;                      // 0..3 quarter-row
      int gr = t0 + c * kCH + row;
      if (gr > kS - 1) gr = kS - 1;                // clamp; masked at consume
      const float* g = xb + (size_t)gr * kH + seg * 256 + col;
      float* l = &lds[c & (kSlots - 1)][row][seg * 256];   // wave-uniform dest
      __builtin_amdgcn_global_load_lds(
          (const __attribute__((address_space(1))) void*)g,
          (__attribute__((address_space(3))) void*)l, 16, 0, 0);
    }
  };

  // ---- prologue: 3 chunks in flight (6 loads/wave outstanding) ----
  stage(0);
  stage(1);
  stage(2);

#pragma unroll
  for (int c = 0; c < kChunks; ++c) {
    // Wait for chunk c only; chunks c+1, c+2 remain in flight across the barrier.
    if (c <= kChunks - 3)      asm volatile("s_waitcnt vmcnt(4)" ::: "memory");
    else if (c == kChunks - 2) asm volatile("s_waitcnt vmcnt(2)" ::: "memory");
    else                       asm volatile("s_waitcnt vmcnt(0)" ::: "memory");
    __builtin_amdgcn_s_barrier();                  // all waves: chunk c resident
    __builtin_amdgcn_sched_barrier(0);

    // Stage chunk c+3 into slot (c+3)%4 (free: last read at iter c-1).
    if (c + 3 < kChunks) stage(c + 3);

    // Pull this wave's queries from the staged data (rows 2w, 2w+1 in chunk w>>1).
    if ((wid >> 1) == c) {
      const int jq = 2 * (wid & 1);
#pragma unroll
      for (int tt = 0; tt < kTPW; ++tt)
#pragma unroll
        for (int p = 0; p < kFR; ++p)
          xt[tt][p] = *(const float4*)&lds[c & (kSlots - 1)][jq + tt][p * 256 + col];
    }

    // ---- consume chunk c ----
#pragma unroll
    for (int jr = 0; jr < kCH; ++jr) {
      const int ri  = c * kCH + jr;                // union-row index (compile-time)
      const int rel = ri - tw;                     // wave-uniform
      if (rel >= 1 && rel <= kTPW - 1 + kK && (t0 + ri) < kS) {
        float4 w[kFR];
#pragma unroll
        for (int p = 0; p < kFR; ++p)
          w[p] = *(const float4*)&lds[c & (kSlots - 1)][jr][p * 256 + col];

        // Branchless dots for both t's (masked at update)
        float sc[kTPW];
#pragma unroll
        for (int tt = 0; tt < kTPW; ++tt) {
          float a0 = 0.f, a1 = 0.f;
#pragma unroll
          for (int p = 0; p < kFR; ++p) {
            a0 = fmaf(xt[tt][p].x, w[p].x, a0);
            a1 = fmaf(xt[tt][p].y, w[p].y, a1);
            a0 = fmaf(xt[tt][p].z, w[p].z, a0);
            a1 = fmaf(xt[tt][p].w, w[p].w, a1);
          }
          sc[tt] = a0 + a1;
        }

        // Batched 64-lane butterfly (2 chains pipeline per level)
#pragma unroll
        for (int off = 32; off >= 1; off >>= 1) {
          float other[kTPW];
#pragma unroll
          for (int tt = 0; tt < kTPW; ++tt) other[tt] = __shfl_xor(sc[tt], off, 64);
#pragma unroll
          for (int tt = 0; tt < kTPW; ++tt) sc[tt] += other[tt];
        }

        // Online-softmax updates (wave-uniform masks and scores)
#pragma unroll
        for (int tt = 0; tt < kTPW; ++tt) {
          const int d = rel - tt;
          if (d >= 1 && d <= kK) {
            const float v = sc[tt];
            if (v <= m[tt]) {
              const float p2 = __expf(v - m[tt]);
              s[tt] += p2;
#pragma unroll
              for (int p = 0; p < kFR; ++p) {
                acc[tt][p].x = fmaf(p2, w[p].x, acc[tt][p].x);
                acc[tt][p].y = fmaf(p2, w[p].y, acc[tt][p].y);
                acc[tt][p].z = fmaf(p2, w[p].z, acc[tt][p].z);
                acc[tt][p].w = fmaf(p2, w[p].w, acc[tt][p].w);
              }
            } else {
              const float r2 = __expf(m[tt] - v);  // 0 on first valid row
              m[tt] = v;
              s[tt] = fmaf(s[tt], r2, 1.f);
#pragma unroll
              for (int p = 0; p < kFR; ++p) {
                acc[tt][p].x = fmaf(acc[tt][p].x, r2, w[p].x);
                acc[tt][p].y = fmaf(acc[tt][p].y, r2, w[p].y);
                acc[tt][p].z = fmaf(acc[tt][p].z, r2, w[p].z);
                acc[tt][p].w = fmaf(acc[tt][p].w, r2, w[p].w);
              }
            }
          }
        }
      }
    }
  }

  // ---- epilogue: out = acc / s  (s==0 only for t==S-1 -> exact zeros) ----
#pragma unroll
  for (int tt = 0; tt < kTPW; ++tt) {
    const float inv = (s[tt] > 0.f) ? (1.f / s[tt]) : 0.f;
    const int t = t0 + tw + tt;
#pragma unroll
    for (int p = 0; p < kFR; ++p) {
      float4 o;
      o.x = acc[tt][p].x * inv;
      o.y = acc[tt][p].y * inv;
      o.z = acc[tt][p].z * inv;
      o.w = acc[tt][p].w * inv;
      *(float4*)(ob + (size_t)t * kH + p * 256 + col) = o;
    }
  }
}

extern "C" void kernel_launch(void* const* d_in, const int* in_sizes, int n_in,
                              void* d_out, int out_size, void* d_ws, size_t ws_size,
                              hipStream_t stream) {
  const float* x = (const float*)d_in[0];
  float* out = (float*)d_out;
  hipLaunchKernelGGL(future_encoder_kernel, dim3(kBlocks), dim3(512), 0, stream,
                     x, out);
}

// Round 11
// 26.153 us; speedup vs baseline: 1.3686x; 1.3686x over previous
//
#include <hip/hip_runtime.h>

// FutureEncoder as banded flash-attention on MFMA (bf16 split-precision).
// out[b,t,:] = softmax_j(x[t]·x[t+1+j]) · x[t+1+j], j in [0,16), fp32 I/O.
//
// Block (512thr, 8 waves) owns 16 t's. Waves k-split H (128 each) for QK^T;
// partial S^T reduced via LDS; softmax fully in-lane (swapped-QK puts all 32
// window scores for one t in one lane's C/D regs); P^T built with 16 shfls;
// PV via 8 mfma/wave with V gathered scalar from global (L1/L2-hot).
// Accuracy: scores via split-bf16 (hi*hi + hi*lo + lo*hi), P/V single bf16.

typedef float f32x4 __attribute__((ext_vector_type(4)));
typedef unsigned int u32;
typedef u32 u32x4 __attribute__((ext_vector_type(4)));
typedef short bf16x8 __attribute__((ext_vector_type(8)));

namespace {
constexpr int kB = 2, kS = 4096, kH = 1024;
constexpr int kWaves = 8;                    // 512 threads
constexpr int kTilesT = 16;                  // t's per block
constexpr int kBlocks = kB * kS / kTilesT;   // 512 -> 2 blocks/CU
constexpr int kXCD = 8;
constexpr int kHW = kH / kWaves;             // 128 h-cols per wave
}

__device__ __forceinline__ u32 f32u(float x){ return __builtin_bit_cast(u32, x); }
__device__ __forceinline__ float uf32(u32 x){ return __builtin_bit_cast(float, x); }
__device__ __forceinline__ u32 pkbf(float a, float b){ return (f32u(b)&0xFFFF0000u)|(f32u(a)>>16); }

struct Frag2 { bf16x8 hi, lo; };
__device__ __forceinline__ Frag2 split2(float4 u, float4 v) {
  float fu[8] = {u.x,u.y,u.z,u.w,v.x,v.y,v.z,v.w};
  u32 hw[4], lw[4];
#pragma unroll
  for (int i = 0; i < 4; ++i) {
    float a = fu[2*i], b = fu[2*i+1];
    u32 ua = f32u(a), ub = f32u(b);
    hw[i] = (ub & 0xFFFF0000u) | (ua >> 16);
    float la = a - uf32(ua & 0xFFFF0000u);
    float lb = b - uf32(ub & 0xFFFF0000u);
    lw[i] = (f32u(lb) & 0xFFFF0000u) | (f32u(la) >> 16);
  }
  Frag2 r;
  u32x4 h = {hw[0],hw[1],hw[2],hw[3]}, l = {lw[0],lw[1],lw[2],lw[3]};
  r.hi = __builtin_bit_cast(bf16x8, h);
  r.lo = __builtin_bit_cast(bf16x8, l);
  return r;
}

#define MFMA(A,B,C) __builtin_amdgcn_mfma_f32_16x16x32_bf16((A),(B),(C),0,0,0)

__global__ __launch_bounds__(512, 4)
void fenc_mfma(const float* __restrict__ x, float* __restrict__ out) {
  __shared__ float red[kWaves][2][4][64];   // 16 KB: per-wave S^T partials
  const int lane = (int)(threadIdx.x & 63), wid = (int)(threadIdx.x >> 6);
  const int g = lane >> 4, c = lane & 15;

  // XCD strip swizzle (512 % 8 == 0 -> bijective)
  const int vb  = (int)(blockIdx.x % kXCD)*(kBlocks/kXCD) + (int)(blockIdx.x / kXCD);
  const int t0g = vb * kTilesT;
  const int b   = t0g / kS, t0 = t0g % kS;
  const float* __restrict__ xb = x + (size_t)b*kS*kH;
  float* __restrict__ ob = out + (size_t)b*kS*kH;
  const int hw0 = kHW * wid;

  // ---- QK^T (swapped: A = K windows, B = Q), k-split over H ----
  const int ra = (t0 + 1 + c  < kS) ? (t0 + 1 + c)  : (kS - 1);
  const int rb = (t0 + 17 + c < kS) ? (t0 + 17 + c) : (kS - 1);
  const float* qp  = xb + (size_t)(t0 + c)*kH + hw0;
  const float* kpa = xb + (size_t)ra*kH + hw0;
  const float* kpb = xb + (size_t)rb*kH + hw0;

  f32x4 accA = {0.f,0.f,0.f,0.f}, accB = {0.f,0.f,0.f,0.f};
#pragma unroll
  for (int ks = 0; ks < 4; ++ks) {
    const int off = ks*32 + g*8;
    float4 q0 = *(const float4*)(qp  + off), q1 = *(const float4*)(qp  + off + 4);
    float4 a0 = *(const float4*)(kpa + off), a1 = *(const float4*)(kpa + off + 4);
    float4 b0 = *(const float4*)(kpb + off), b1 = *(const float4*)(kpb + off + 4);
    Frag2 fq = split2(q0, q1), fa = split2(a0, a1), fb = split2(b0, b1);
    accA = MFMA(fa.hi, fq.hi, accA);
    accA = MFMA(fa.hi, fq.lo, accA);
    accA = MFMA(fa.lo, fq.hi, accA);
    accB = MFMA(fb.hi, fq.hi, accB);
    accB = MFMA(fb.hi, fq.lo, accB);
    accB = MFMA(fb.lo, fq.hi, accB);
  }

  // ---- cross-wave reduce of S^T partials (lane-linear, conflict-free) ----
#pragma unroll
  for (int r = 0; r < 4; ++r) {
    red[wid][0][r][lane] = accA[r];
    red[wid][1][r][lane] = accB[r];
  }
  __syncthreads();
#pragma unroll
  for (int w = 0; w < kWaves; ++w) {
    if (w != wid) {
#pragma unroll
      for (int r = 0; r < 4; ++r) {
        accA[r] += red[w][0][r][lane];
        accB[r] += red[w][1][r][lane];
      }
    }
  }

  // ---- softmax (per lane: all 32 windows of t = t0+c live in accA/accB) ----
  // C/D layout (verified): value at (window = 4g+r + 16T, t = c).
  float p[2][4];
  float vmax = -1e30f;
#pragma unroll
  for (int T = 0; T < 2; ++T)
#pragma unroll
    for (int r = 0; r < 4; ++r) {
      const int w = 16*T + 4*g + r;
      const bool val = (w >= c) && (w < c + 16) && (t0 + 1 + w < kS);
      const float sv = val ? (T ? accB[r] : accA[r]) : -1e30f;
      p[T][r] = sv;
      vmax = fmaxf(vmax, sv);
    }
  vmax = fmaxf(vmax, __shfl_xor(vmax, 16, 64));
  vmax = fmaxf(vmax, __shfl_xor(vmax, 32, 64));
  float psum = 0.f;
#pragma unroll
  for (int T = 0; T < 2; ++T)
#pragma unroll
    for (int r = 0; r < 4; ++r) {
      const int w = 16*T + 4*g + r;
      const bool val = (w >= c) && (w < c + 16) && (t0 + 1 + w < kS);
      const float e = val ? __expf(p[T][r] - vmax) : 0.f;
      p[T][r] = e;
      psum += e;
    }
  psum += __shfl_xor(psum, 16, 64);
  psum += __shfl_xor(psum, 32, 64);
  const float inv = (psum > 0.f) ? (1.f / psum) : 0.f;
#pragma unroll
  for (int T = 0; T < 2; ++T)
#pragma unroll
    for (int r = 0; r < 4; ++r) p[T][r] *= inv;

  // ---- build P^T A-frag: lane needs P[t=c][w = 8g+i], i=0..7 ----
  const int se = (g & 1)*32 + c, so = se + 16;
  float slot[8];
#pragma unroll
  for (int r = 0; r < 4; ++r) {
    const float e0 = __shfl(p[0][r], se, 64), e1 = __shfl(p[1][r], se, 64);
    const float o0 = __shfl(p[0][r], so, 64), o1 = __shfl(p[1][r], so, 64);
    slot[r]     = (g >> 1) ? e1 : e0;
    slot[4 + r] = (g >> 1) ? o1 : o0;
  }
  u32x4 pw = { pkbf(slot[0],slot[1]), pkbf(slot[2],slot[3]),
               pkbf(slot[4],slot[5]), pkbf(slot[6],slot[7]) };
  const bf16x8 pa = __builtin_bit_cast(bf16x8, pw);

  // ---- PV: O[t][h] = sum_w P[t][w] V[w][h]; wave covers h in [hw0, hw0+128) ----
  const float* vrow[8];
#pragma unroll
  for (int i = 0; i < 8; ++i) {
    const int rv = t0 + 1 + 8*g + i;
    vrow[i] = xb + (size_t)((rv < kS) ? rv : (kS - 1))*kH + hw0 + c;
  }
  f32x4 o[8];
#pragma unroll
  for (int nt = 0; nt < 8; ++nt) {
    float vf[8];
#pragma unroll
    for (int i = 0; i < 8; ++i) vf[i] = vrow[i][16*nt];
    u32x4 vw = { pkbf(vf[0],vf[1]), pkbf(vf[2],vf[3]),
                 pkbf(vf[4],vf[5]), pkbf(vf[6],vf[7]) };
    const bf16x8 vfrag = __builtin_bit_cast(bf16x8, vw);
    f32x4 z = {0.f,0.f,0.f,0.f};
    o[nt] = MFMA(pa, vfrag, z);
  }

  // ---- store: C/D layout -> O[t = t0+4g+r][h = hw0 + 16nt + c] ----
  float* orow[4];
#pragma unroll
  for (int r = 0; r < 4; ++r)
    orow[r] = ob + (size_t)(t0 + 4*g + r)*kH + hw0 + c;
#pragma unroll
  for (int nt = 0; nt < 8; ++nt)
#pragma unroll
    for (int r = 0; r < 4; ++r)
      orow[r][16*nt] = o[nt][r];
}

extern "C" void kernel_launch(void* const* d_in, const int* in_sizes, int n_in,
                              void* d_out, int out_size, void* d_ws, size_t ws_size,
                              hipStream_t stream) {
  const float* x = (const float*)d_in[0];
  float* out = (float*)d_out;
  hipLaunchKernelGGL(fenc_mfma, dim3(kBlocks), dim3(512), 0, stream, x, out);
}